// Round 2
// baseline (494.729 us; speedup 1.0000x reference)
//
#include <hip/hip_runtime.h>
#include <cstdint>

#define Ltok 4096
#define Dm   2048

typedef __attribute__((ext_vector_type(8))) short short8;
typedef __attribute__((ext_vector_type(4))) float f32x4;

__device__ __forceinline__ ushort f2bf(float x) {
  union { float f; uint32_t u; } v; v.f = x;
  uint32_t r = v.u + 0x7FFFu + ((v.u >> 16) & 1u);
  return (ushort)(r >> 16);
}

typedef __attribute__((address_space(1))) void gv_t;
typedef __attribute__((address_space(3))) void lv_t;
__device__ __forceinline__ void lds_load16(const void* g, void* l) {
  __builtin_amdgcn_global_load_lds((gv_t*)g, (lv_t*)l, 16, 0, 0);
}

// ---------------------------------------------------------------------------
// prep: per-token row norm + bf16 cast of token_vecs
__global__ __launch_bounds__(256) void prep_tokens(const float* __restrict__ T,
                                                   ushort* __restrict__ Tbf,
                                                   float* __restrict__ aArr) {
  __shared__ float red[4];
  const int tid = threadIdx.x, lane = tid & 63, w = tid >> 6;
  const float* rp = T + (size_t)blockIdx.x * Dm;
  ushort* op = Tbf + (size_t)blockIdx.x * Dm;
  float ss = 0.f;
  for (int j = tid * 4; j < Dm; j += 1024) {
    float4 v = *(const float4*)&rp[j];
    ss += v.x * v.x + v.y * v.y + v.z * v.z + v.w * v.w;
    ushort4 o; o.x = f2bf(v.x); o.y = f2bf(v.y); o.z = f2bf(v.z); o.w = f2bf(v.w);
    *(ushort4*)&op[j] = o;
  }
#pragma unroll
  for (int off = 32; off > 0; off >>= 1) ss += __shfl_xor(ss, off);
  if (lane == 0) red[w] = ss;
  __syncthreads();
  if (tid == 0) {
    float n = sqrtf(red[0] + red[1] + red[2] + red[3]);
    aArr[blockIdx.x] = n / (n + 1e-8f);   // mass/(norm+eps) factor
  }
}

__global__ __launch_bounds__(256) void cast_f32_bf16(const float* __restrict__ in,
                                                     ushort* __restrict__ out, int n) {
  int i = (blockIdx.x * 256 + threadIdx.x) * 4;
  if (i + 3 < n) {
    float4 v = *(const float4*)&in[i];
    ushort4 o; o.x = f2bf(v.x); o.y = f2bf(v.y); o.z = f2bf(v.z); o.w = f2bf(v.w);
    *(ushort4*)&out[i] = o;
  }
}

__global__ void small_prep(const float* __restrict__ G, const float* __restrict__ R,
                           const int* __restrict__ depth,
                           float* __restrict__ sigG, float* __restrict__ sigR,
                           float* __restrict__ rad) {
  int tid = threadIdx.x;
  if (tid < 64) {
    sigG[tid] = 1.0f / (1.0f + expf(-G[tid]));
    sigR[tid] = 1.0f / (1.0f + expf(-R[tid]));
  }
  for (int i = tid; i < Ltok; i += 256) {
    int d = depth[i];
    rad[i] = (d <= 0) ? 1.0f : (d == 1 ? 3.0f : 9.0f);   // 3^d exactly
  }
}

// ---------------------------------------------------------------------------
// C = A @ B^T, A:[M][K] bf16, B:[N][K] bf16.  128x128 tile, BK=32, 4 waves.
// MODE 0: scores epilogue -> f32 (scale by c_ij, zero diag)
// MODE 1: +bias -> bf16   MODE 2: plain -> bf16   MODE 3: +bias -> f32
template <int MODE>
__global__ __launch_bounds__(256) void gemm_bt(
    const ushort* __restrict__ A, const ushort* __restrict__ B,
    int M, int N, int K,
    float* __restrict__ Cf, ushort* __restrict__ Cbf,
    const float* __restrict__ bias,
    const float* __restrict__ aArr, const float* __restrict__ radArr,
    const float* __restrict__ eccArr, const int* __restrict__ posArr,
    const float* __restrict__ sigG, const float* __restrict__ sigR)
{
  __shared__ ushort sA[128 * 32];
  __shared__ ushort sB[128 * 32];
  const int tid = threadIdx.x;
  const int lane = tid & 63;
  const int w = tid >> 6;
  const int wr = w >> 1, wc = w & 1;
  const int bm = blockIdx.y * 128, bn = blockIdx.x * 128;
  const int fr = lane & 15, fq = lane >> 4;

  f32x4 acc[4][4] = {};

  for (int kt = 0; kt < K; kt += 32) {
    __syncthreads();
#pragma unroll
    for (int s = 0; s < 2; ++s) {
      const int q = w * 2 + s;              // wave-uniform chunk id 0..7
      const int e = q * 512 + lane * 8;     // element offset in tile
      const int r = e >> 5, c = e & 31;
      lds_load16(&A[(size_t)(bm + r) * K + kt + c], &sA[q * 512]);
      lds_load16(&B[(size_t)(bn + r) * K + kt + c], &sB[q * 512]);
    }
    __syncthreads();
    short8 af[4], bfr[4];
#pragma unroll
    for (int m = 0; m < 4; ++m)
      af[m] = *(const short8*)&sA[(wr * 64 + m * 16 + fr) * 32 + fq * 8];
#pragma unroll
    for (int n = 0; n < 4; ++n)
      bfr[n] = *(const short8*)&sB[(wc * 64 + n * 16 + fr) * 32 + fq * 8];
#pragma unroll
    for (int m = 0; m < 4; ++m)
#pragma unroll
      for (int n = 0; n < 4; ++n)
        acc[m][n] = __builtin_amdgcn_mfma_f32_16x16x32_bf16(af[m], bfr[n], acc[m][n], 0, 0, 0);
  }

#pragma unroll
  for (int n = 0; n < 4; ++n) {
    const int gj = bn + wc * 64 + n * 16 + fr;
    float colA = 0.f, colE = 0.f, colR = 0.f, colB = 0.f;
    int pj = 0;
    if constexpr (MODE == 0) {
      colA = aArr[gj]; colE = eccArr[gj]; colR = radArr[gj]; pj = posArr[gj];
    } else if constexpr (MODE == 1 || MODE == 3) {
      colB = bias[gj];
    }
#pragma unroll
    for (int m = 0; m < 4; ++m) {
      f32x4 v = acc[m][n];
#pragma unroll
      for (int r = 0; r < 4; ++r) {
        const int gi = bm + wr * 64 + m * 16 + fq * 4 + r;
        float x = v[r];
        if constexpr (MODE == 0) {
          float rr = fabsf(radArr[gi] - colR) + 1.0f;
          int pi = posArr[gi];
          float cij = sigG[pi * 8 + pj] * sigR[pi * 8 + pj] *
                      (1.0f - eccArr[gi] * colE) * aArr[gi] * colA / (rr * rr);
          x *= cij;
          if (gi == gj) x = 0.0f;
          Cf[(size_t)gi * N + gj] = x;
        } else if constexpr (MODE == 3) {
          Cf[(size_t)gi * N + gj] = x + colB;
        } else if constexpr (MODE == 1) {
          Cbf[(size_t)gi * N + gj] = f2bf(x + colB);
        } else {
          Cbf[(size_t)gi * N + gj] = f2bf(x);
        }
      }
    }
  }
}

// ---------------------------------------------------------------------------
// row softmax over f32 scores; f32 A out (d_out) + bf16 A out (ws)
__global__ __launch_bounds__(256) void softmax_rows(const float* __restrict__ S,
                                                    float* __restrict__ Af,
                                                    ushort* __restrict__ Abf) {
  __shared__ float buf[Ltok];
  __shared__ float red[4];
  const int tid = threadIdx.x, lane = tid & 63, w = tid >> 6;
  const float* sr = S + (size_t)blockIdx.x * Ltok;
  float lmax = -3.4e38f;
  for (int j = tid * 4; j < Ltok; j += 1024) {
    float4 v = *(const float4*)&sr[j];
    *(float4*)&buf[j] = v;
    lmax = fmaxf(fmaxf(lmax, fmaxf(v.x, v.y)), fmaxf(v.z, v.w));
  }
#pragma unroll
  for (int off = 32; off > 0; off >>= 1) lmax = fmaxf(lmax, __shfl_xor(lmax, off));
  if (lane == 0) red[w] = lmax;
  __syncthreads();
  const float m = fmaxf(fmaxf(red[0], red[1]), fmaxf(red[2], red[3]));
  __syncthreads();
  float lsum = 0.f;
  for (int j = tid * 4; j < Ltok; j += 1024) {
    lsum += expf(buf[j] - m) + expf(buf[j + 1] - m) +
            expf(buf[j + 2] - m) + expf(buf[j + 3] - m);
  }
#pragma unroll
  for (int off = 32; off > 0; off >>= 1) lsum += __shfl_xor(lsum, off);
  if (lane == 0) red[w] = lsum;
  __syncthreads();
  const float inv = 1.0f / (red[0] + red[1] + red[2] + red[3]);
  float* arf = Af + (size_t)blockIdx.x * Ltok;
  ushort* arb = Abf + (size_t)blockIdx.x * Ltok;
  for (int j = tid * 4; j < Ltok; j += 1024) {
    float4 a;
    a.x = expf(buf[j] - m) * inv;
    a.y = expf(buf[j + 1] - m) * inv;
    a.z = expf(buf[j + 2] - m) * inv;
    a.w = expf(buf[j + 3] - m) * inv;
    *(float4*)&arf[j] = a;
    ushort4 o; o.x = f2bf(a.x); o.y = f2bf(a.y); o.z = f2bf(a.z); o.w = f2bf(a.w);
    *(ushort4*)&arb[j] = o;
  }
}

// ---------------------------------------------------------------------------
// out[c][r] = in[r][c], bf16, 64x64 tiles
__global__ __launch_bounds__(256) void transpose_bf16(const ushort* __restrict__ in,
                                                      ushort* __restrict__ out,
                                                      int R, int C) {
  __shared__ ushort tile[64][65];
  const int tx = threadIdx.x & 63, ty = threadIdx.x >> 6;
  const int c0 = blockIdx.x * 64, r0 = blockIdx.y * 64;
  for (int r = ty; r < 64; r += 4)
    tile[r][tx] = in[(size_t)(r0 + r) * C + c0 + tx];
  __syncthreads();
  for (int r = ty; r < 64; r += 4)
    out[(size_t)(c0 + r) * R + r0 + tx] = tile[tx][r];
}

// ---------------------------------------------------------------------------
extern "C" void kernel_launch(void* const* d_in, const int* in_sizes, int n_in,
                              void* d_out, int out_size, void* d_ws, size_t ws_size,
                              hipStream_t stream) {
  const float* tok = (const float*)d_in[0];
  const float* ecc = (const float*)d_in[1];
  const float* Gm  = (const float*)d_in[2];
  const float* Rm  = (const float*)d_in[3];
  const float* Wv  = (const float*)d_in[4];
  const float* bv  = (const float*)d_in[5];
  const float* Wo  = (const float*)d_in[6];
  const float* bo  = (const float*)d_in[7];
  const int*   pos = (const int*)d_in[8];
  const int*   dep = (const int*)d_in[9];

  float* out_f = (float*)d_out;                    // [L][D] f32
  float* A_f   = out_f + (size_t)Ltok * Dm;        // [L][L] f32
  float* S_f   = A_f + (size_t)Ltok * Ltok;        // [L][L] f32

  char* ws = (char*)d_ws;
  size_t off = 0;
  auto alloc = [&](size_t bytes) {
    void* p = ws + off; off = (off + bytes + 255) & ~(size_t)255; return p;
  };
  ushort* Tbf  = (ushort*)alloc((size_t)Ltok * Dm * 2);   // 16 MB
  ushort* Wvbf = (ushort*)alloc((size_t)Dm * Dm * 2);     //  8 MB
  ushort* Wobf = (ushort*)alloc((size_t)Dm * Dm * 2);     //  8 MB
  ushort* Vbf  = (ushort*)alloc((size_t)Ltok * Dm * 2);   // 16 MB
  ushort* Vt   = (ushort*)alloc((size_t)Dm * Ltok * 2);   // 16 MB
  ushort* Abf  = (ushort*)alloc((size_t)Ltok * Ltok * 2); // 32 MB
  ushort* AVbf = (ushort*)alloc((size_t)Ltok * Dm * 2);   // 16 MB
  float*  aArr = (float*)alloc(Ltok * 4);
  float*  rad  = (float*)alloc(Ltok * 4);
  float*  sigG = (float*)alloc(64 * 4);
  float*  sigR = (float*)alloc(64 * 4);

  prep_tokens<<<Ltok, 256, 0, stream>>>(tok, Tbf, aArr);
  cast_f32_bf16<<<(Dm * Dm) / 1024, 256, 0, stream>>>(Wv, Wvbf, Dm * Dm);
  cast_f32_bf16<<<(Dm * Dm) / 1024, 256, 0, stream>>>(Wo, Wobf, Dm * Dm);
  small_prep<<<1, 256, 0, stream>>>(Gm, Rm, dep, sigG, sigR, rad);

  // scores = c_ij * (Tbf @ Tbf^T)  -> f32 into d_out scores region
  gemm_bt<0><<<dim3(Ltok / 128, Ltok / 128), 256, 0, stream>>>(
      Tbf, Tbf, Ltok, Ltok, Dm, S_f, nullptr, nullptr, aArr, rad, ecc, pos, sigG, sigR);
  // A = softmax(scores) -> f32 A into d_out, bf16 copy into ws
  softmax_rows<<<Ltok, 256, 0, stream>>>(S_f, A_f, Abf);

  // V = T @ Wv^T + bv  -> bf16 (intermediate only)
  gemm_bt<1><<<dim3(Dm / 128, Ltok / 128), 256, 0, stream>>>(
      Tbf, Wvbf, Ltok, Dm, Dm, nullptr, Vbf, bv,
      nullptr, nullptr, nullptr, nullptr, nullptr, nullptr);
  transpose_bf16<<<dim3(Dm / 64, Ltok / 64), 256, 0, stream>>>(Vbf, Vt, Ltok, Dm);

  // AV = A @ V  (B^T operand = Vt) -> bf16
  gemm_bt<2><<<dim3(Dm / 128, Ltok / 128), 256, 0, stream>>>(
      Abf, Vt, Ltok, Dm, Ltok, nullptr, AVbf, nullptr,
      nullptr, nullptr, nullptr, nullptr, nullptr, nullptr);

  // out = AV @ Wo^T + bo -> f32 into d_out
  gemm_bt<3><<<dim3(Dm / 128, Ltok / 128), 256, 0, stream>>>(
      AVbf, Wobf, Ltok, Dm, Dm, out_f, nullptr, bo,
      nullptr, nullptr, nullptr, nullptr, nullptr, nullptr);
}

// Round 3
// 333.471 us; speedup vs baseline: 1.4836x; 1.4836x over previous
//
#include <hip/hip_runtime.h>
#include <cstdint>

#define Ltok 4096
#define Dm   2048

typedef __attribute__((ext_vector_type(8))) short short8;
typedef __attribute__((ext_vector_type(4))) float f32x4;

__device__ __forceinline__ ushort f2bf(float x) {
  union { float f; uint32_t u; } v; v.f = x;
  uint32_t r = v.u + 0x7FFFu + ((v.u >> 16) & 1u);
  return (ushort)(r >> 16);
}

typedef __attribute__((address_space(1))) void gv_t;
typedef __attribute__((address_space(3))) void lv_t;
__device__ __forceinline__ void lds_load16(const void* g, void* l) {
  __builtin_amdgcn_global_load_lds((gv_t*)g, (lv_t*)l, 16, 0, 0);
}

// ---------------------------------------------------------------------------
// prep: per-token row norm + bf16 cast + packed per-token epilogue params
__global__ __launch_bounds__(256) void prep_tokens(const float* __restrict__ T,
                                                   const float* __restrict__ ecc,
                                                   const int* __restrict__ pos,
                                                   const int* __restrict__ dep,
                                                   ushort* __restrict__ Tbf,
                                                   float4* __restrict__ tokf4) {
  __shared__ float red[4];
  const int tid = threadIdx.x, lane = tid & 63, w = tid >> 6;
  const int row = blockIdx.x;
  const float* rp = T + (size_t)row * Dm;
  ushort* op = Tbf + (size_t)row * Dm;
  float ss = 0.f;
  for (int j = tid * 4; j < Dm; j += 1024) {
    float4 v = *(const float4*)&rp[j];
    ss += v.x * v.x + v.y * v.y + v.z * v.z + v.w * v.w;
    ushort4 o; o.x = f2bf(v.x); o.y = f2bf(v.y); o.z = f2bf(v.z); o.w = f2bf(v.w);
    *(ushort4*)&op[j] = o;
  }
#pragma unroll
  for (int off = 32; off > 0; off >>= 1) ss += __shfl_xor(ss, off);
  if (lane == 0) red[w] = ss;
  __syncthreads();
  if (tid == 0) {
    float n = sqrtf(red[0] + red[1] + red[2] + red[3]);
    int d = dep[row];
    float4 t;
    t.x = n / (n + 1e-8f);                         // mass/(norm+eps)
    t.y = ecc[row];
    t.z = (d <= 0) ? 1.0f : (d == 1 ? 3.0f : 9.0f); // radius = 3^d
    t.w = (float)pos[row];
    tokf4[row] = t;
  }
}

__global__ __launch_bounds__(256) void cast_f32_bf16(const float* __restrict__ in,
                                                     ushort* __restrict__ out, int n) {
  int i = (blockIdx.x * 256 + threadIdx.x) * 4;
  if (i + 3 < n) {
    float4 v = *(const float4*)&in[i];
    ushort4 o; o.x = f2bf(v.x); o.y = f2bf(v.y); o.z = f2bf(v.z); o.w = f2bf(v.w);
    *(ushort4*)&out[i] = o;
  }
}

__global__ void small_prep(const float* __restrict__ G, const float* __restrict__ R,
                           float* __restrict__ sGR) {
  int tid = threadIdx.x;
  if (tid < 64) {
    float g = 1.0f / (1.0f + expf(-G[tid]));
    float r = 1.0f / (1.0f + expf(-R[tid]));
    sGR[tid] = g * r;
  }
}

// ---------------------------------------------------------------------------
// C = A @ B^T, A:[M][KDIM] bf16, B:[NDIM][KDIM] bf16.  128x128 tile, BK=32.
// MODE 0: scores epilogue -> f32 (c_ij scale, zero diag)
// MODE 1: +row bias -> bf16   MODE 2: plain -> bf16   MODE 3: +col bias -> f32
template <int MODE, int NDIM, int KDIM>
__global__ __launch_bounds__(256) void gemm_bt(
    const ushort* __restrict__ A, const ushort* __restrict__ B,
    float* __restrict__ Cf, ushort* __restrict__ Cbf,
    const float* __restrict__ bias,
    const float4* __restrict__ tokf4, const float* __restrict__ sGR)
{
  __shared__ ushort sA[128 * 32];
  __shared__ ushort sB[128 * 32];
  __shared__ float sGRl[64];
  const int tid = threadIdx.x;
  const int lane = tid & 63;
  const int w = tid >> 6;
  const int wr = w >> 1, wc = w & 1;

  // XCD-aware swizzle (nwg is always a multiple of 8 here)
  int gx = gridDim.x, gy = gridDim.y;
  int bid = blockIdx.y * gx + blockIdx.x;
  int cpx = (gx * gy) >> 3;
  int sbid = (bid & 7) * cpx + (bid >> 3);
  const int bn = (sbid % gx) * 128;
  const int bm = (sbid / gx) * 128;

  const int fr = lane & 15, fq = lane >> 4;

  if constexpr (MODE == 0) {
    if (tid < 64) sGRl[tid] = sGR[tid];
  }

  // staging source pointers (per-thread, loop-invariant)
  const int q = w * 2;
  const int e0 = q * 512 + lane * 8;
  const int rA = e0 >> 5, cA = e0 & 31;        // s = 0
  const ushort* gA0 = A + (size_t)(bm + rA) * KDIM + cA;
  const ushort* gA1 = A + (size_t)(bm + rA + 16) * KDIM + cA;
  const ushort* gB0 = B + (size_t)(bn + rA) * KDIM + cA;
  const ushort* gB1 = B + (size_t)(bn + rA + 16) * KDIM + cA;
  ushort* lA0 = &sA[q * 512], *lA1 = &sA[q * 512 + 512];
  ushort* lB0 = &sB[q * 512], *lB1 = &sB[q * 512 + 512];
  const ushort* fA = &sA[(wr * 64 + fr) * 32 + fq * 8];
  const ushort* fB = &sB[(wc * 64 + fr) * 32 + fq * 8];

  f32x4 acc[4][4] = {};

  for (int kt = 0; kt < KDIM; kt += 32) {
    __syncthreads();
    lds_load16(gA0 + kt, lA0);
    lds_load16(gA1 + kt, lA1);
    lds_load16(gB0 + kt, lB0);
    lds_load16(gB1 + kt, lB1);
    __syncthreads();
    short8 af[4], bfr[4];
#pragma unroll
    for (int m = 0; m < 4; ++m) af[m] = *(const short8*)(fA + m * 16 * 32);
#pragma unroll
    for (int n = 0; n < 4; ++n) bfr[n] = *(const short8*)(fB + n * 16 * 32);
#pragma unroll
    for (int m = 0; m < 4; ++m)
#pragma unroll
      for (int n = 0; n < 4; ++n)
        acc[m][n] = __builtin_amdgcn_mfma_f32_16x16x32_bf16(af[m], bfr[n], acc[m][n], 0, 0, 0);
  }

  // ---- epilogue ----
  const int gj0 = bn + wc * 64 + fr;
  const int gi0 = bm + wr * 64 + fq * 4;

  float4 cj4[4];
  float colB[4];
  if constexpr (MODE == 0) {
#pragma unroll
    for (int n = 0; n < 4; ++n) cj4[n] = tokf4[gj0 + n * 16];
  } else if constexpr (MODE == 3) {
#pragma unroll
    for (int n = 0; n < 4; ++n) colB[n] = bias[gj0 + n * 16];
  }

#pragma unroll
  for (int m = 0; m < 4; ++m) {
    float4 ci4[4];
    float rb[4];
    if constexpr (MODE == 0) {
#pragma unroll
      for (int r = 0; r < 4; ++r) ci4[r] = tokf4[gi0 + m * 16 + r];
    } else if constexpr (MODE == 1) {
#pragma unroll
      for (int r = 0; r < 4; ++r) rb[r] = bias[gi0 + m * 16 + r];
    }
#pragma unroll
    for (int n = 0; n < 4; ++n) {
      const int gj = gj0 + n * 16;
      f32x4 v = acc[m][n];
#pragma unroll
      for (int r = 0; r < 4; ++r) {
        const int gi = gi0 + m * 16 + r;
        float x = v[r];
        if constexpr (MODE == 0) {
          float rr = fabsf(ci4[r].z - cj4[n].z) + 1.0f;
          int pi = (int)ci4[r].w, pj = (int)cj4[n].w;
          float c = sGRl[pi * 8 + pj] * (1.0f - ci4[r].y * cj4[n].y) *
                    (ci4[r].x * cj4[n].x) * __builtin_amdgcn_rcpf(rr * rr);
          x *= c;
          if (gi == gj) x = 0.0f;
          Cf[(size_t)gi * NDIM + gj] = x;
        } else if constexpr (MODE == 1) {
          Cbf[(size_t)gi * NDIM + gj] = f2bf(x + rb[r]);
        } else if constexpr (MODE == 2) {
          Cbf[(size_t)gi * NDIM + gj] = f2bf(x);
        } else {
          Cf[(size_t)gi * NDIM + gj] = x + colB[n];
        }
      }
    }
  }
}

// ---------------------------------------------------------------------------
// row softmax over f32 scores; f32 A out (d_out) + bf16 A out (ws)
__global__ __launch_bounds__(256) void softmax_rows(const float* __restrict__ S,
                                                    float* __restrict__ Af,
                                                    ushort* __restrict__ Abf) {
  __shared__ float buf[Ltok];
  __shared__ float red[4];
  const int tid = threadIdx.x, lane = tid & 63, w = tid >> 6;
  const float LOG2E = 1.44269504088896f;
  const float* sr = S + (size_t)blockIdx.x * Ltok;
  float lmax = -3.4e38f;
  for (int j = tid * 4; j < Ltok; j += 1024) {
    float4 v = *(const float4*)&sr[j];
    *(float4*)&buf[j] = v;
    lmax = fmaxf(fmaxf(lmax, fmaxf(v.x, v.y)), fmaxf(v.z, v.w));
  }
#pragma unroll
  for (int off = 32; off > 0; off >>= 1) lmax = fmaxf(lmax, __shfl_xor(lmax, off));
  if (lane == 0) red[w] = lmax;
  __syncthreads();
  const float m = fmaxf(fmaxf(red[0], red[1]), fmaxf(red[2], red[3])) * LOG2E;
  __syncthreads();
  float lsum = 0.f;
  for (int j = tid * 4; j < Ltok; j += 1024) {
    lsum += exp2f(buf[j] * LOG2E - m) + exp2f(buf[j + 1] * LOG2E - m) +
            exp2f(buf[j + 2] * LOG2E - m) + exp2f(buf[j + 3] * LOG2E - m);
  }
#pragma unroll
  for (int off = 32; off > 0; off >>= 1) lsum += __shfl_xor(lsum, off);
  if (lane == 0) red[w] = lsum;
  __syncthreads();
  const float inv = 1.0f / (red[0] + red[1] + red[2] + red[3]);
  float* arf = Af + (size_t)blockIdx.x * Ltok;
  ushort* arb = Abf + (size_t)blockIdx.x * Ltok;
  for (int j = tid * 4; j < Ltok; j += 1024) {
    float4 a;
    a.x = exp2f(buf[j] * LOG2E - m) * inv;
    a.y = exp2f(buf[j + 1] * LOG2E - m) * inv;
    a.z = exp2f(buf[j + 2] * LOG2E - m) * inv;
    a.w = exp2f(buf[j + 3] * LOG2E - m) * inv;
    *(float4*)&arf[j] = a;
    ushort4 o; o.x = f2bf(a.x); o.y = f2bf(a.y); o.z = f2bf(a.z); o.w = f2bf(a.w);
    *(ushort4*)&arb[j] = o;
  }
}

// ---------------------------------------------------------------------------
extern "C" void kernel_launch(void* const* d_in, const int* in_sizes, int n_in,
                              void* d_out, int out_size, void* d_ws, size_t ws_size,
                              hipStream_t stream) {
  const float* tok = (const float*)d_in[0];
  const float* ecc = (const float*)d_in[1];
  const float* Gm  = (const float*)d_in[2];
  const float* Rm  = (const float*)d_in[3];
  const float* Wv  = (const float*)d_in[4];
  const float* bv  = (const float*)d_in[5];
  const float* Wo  = (const float*)d_in[6];
  const float* bo  = (const float*)d_in[7];
  const int*   pos = (const int*)d_in[8];
  const int*   dep = (const int*)d_in[9];

  float* out_f = (float*)d_out;                    // [L][D] f32
  float* A_f   = out_f + (size_t)Ltok * Dm;        // [L][L] f32
  float* S_f   = A_f + (size_t)Ltok * Ltok;        // [L][L] f32

  char* ws = (char*)d_ws;
  size_t off = 0;
  auto alloc = [&](size_t bytes) {
    void* p = ws + off; off = (off + bytes + 255) & ~(size_t)255; return p;
  };
  ushort* Tbf  = (ushort*)alloc((size_t)Ltok * Dm * 2);   // 16 MB
  ushort* Wvbf = (ushort*)alloc((size_t)Dm * Dm * 2);     //  8 MB
  ushort* Wobf = (ushort*)alloc((size_t)Dm * Dm * 2);     //  8 MB
  ushort* Vt   = (ushort*)alloc((size_t)Dm * Ltok * 2);   // 16 MB (V^T [D][L])
  ushort* Abf  = (ushort*)alloc((size_t)Ltok * Ltok * 2); // 32 MB
  ushort* AVbf = (ushort*)alloc((size_t)Ltok * Dm * 2);   // 16 MB
  float4* tokf4 = (float4*)alloc(Ltok * 16);
  float*  sGR  = (float*)alloc(64 * 4);

  prep_tokens<<<Ltok, 256, 0, stream>>>(tok, ecc, pos, dep, Tbf, tokf4);
  cast_f32_bf16<<<(Dm * Dm) / 1024, 256, 0, stream>>>(Wv, Wvbf, Dm * Dm);
  cast_f32_bf16<<<(Dm * Dm) / 1024, 256, 0, stream>>>(Wo, Wobf, Dm * Dm);
  small_prep<<<1, 64, 0, stream>>>(Gm, Rm, sGR);

  // scores = c_ij * (Tbf @ Tbf^T)  -> f32 into d_out scores region
  gemm_bt<0, Ltok, Dm><<<dim3(Ltok / 128, Ltok / 128), 256, 0, stream>>>(
      Tbf, Tbf, S_f, nullptr, nullptr, tokf4, sGR);
  // A = softmax(scores) -> f32 A into d_out, bf16 copy into ws
  softmax_rows<<<Ltok, 256, 0, stream>>>(S_f, A_f, Abf);

  // V^T[d][l] = sum_k Wv[d][k] T[l][k] + bv[d]   (row bias)
  gemm_bt<1, Ltok, Dm><<<dim3(Ltok / 128, Dm / 128), 256, 0, stream>>>(
      Wvbf, Tbf, nullptr, Vt, bv, nullptr, nullptr);

  // AV = A @ V  (B^T operand = Vt) -> bf16
  gemm_bt<2, Dm, Ltok><<<dim3(Dm / 128, Ltok / 128), 256, 0, stream>>>(
      Abf, Vt, nullptr, AVbf, nullptr, nullptr, nullptr);

  // out = AV @ Wo^T + bo -> f32 into d_out
  gemm_bt<3, Dm, Dm><<<dim3(Dm / 128, Ltok / 128), 256, 0, stream>>>(
      AVbf, Wobf, out_f, nullptr, bo, nullptr, nullptr);
}